// Round 1
// baseline (359.048 us; speedup 1.0000x reference)
//
#include <hip/hip_runtime.h>
#include <math.h>

#define NB      32768
#define NMODELS 64
#define HID     64
#define LSTR    65          // LDS row stride (pad) -> (s*65+i)%32 = (s+i)%32, conflict-free

// workspace layout (int32 indices)
#define WS_NT    0
#define WS_HIST  16
#define WS_CUR   96
#define WS_TILES 192        // 3 ints per tile, up to 576 tiles
#define WS_SEL   2048
#define WS_PERM  34816
#define MAX_TILES 576       // 64 + 32768/64

// output layout (float32 indices)
#define OUT_SEL  393216
#define OUT_LOG  425984
#define OUT_PROB 2523136

__global__ void k_init(int* __restrict__ wsi) {
  int t = threadIdx.x;
  if (t < NMODELS) wsi[WS_HIST + t] = 0;
}

__global__ void k_fill(float* __restrict__ out) {
  int t = blockIdx.x * 256 + threadIdx.x;   // 524288 threads, 1 float4 each per array
  float4 one = make_float4(1.f, 1.f, 1.f, 1.f);
  float4 pr  = make_float4(0.015625f, 0.015625f, 0.015625f, 0.015625f);
  reinterpret_cast<float4*>(out + OUT_LOG)[t]  = one;
  reinterpret_cast<float4*>(out + OUT_PROB)[t] = pr;
}

__global__ void k_route(const float* __restrict__ in, float* __restrict__ out,
                        int* __restrict__ wsi) {
  __shared__ int lh[NMODELS];
  int t = threadIdx.x;
  if (t < NMODELS) lh[t] = 0;
  __syncthreads();
  int b = blockIdx.x * 256 + t;
  float x = in[b * 6 + 0];
  float z = in[b * 6 + 2];
  const float TWO_PI = 6.283185307179586476925286766559f;
  // f64 atan2 rounded to f32 ~= correctly-rounded f32 atan2 (matches numpy);
  // remaining chain is IEEE-exact f32, bit-identical to the reference.
  float ang = (float)atan2((double)z, (double)x);
  float tt  = ang + TWO_PI;
  float m   = fmodf(tt, TWO_PI);
  float a   = m / TWO_PI * 64.0f;
  int e = (int)floorf(a);
  e = e < 0 ? 0 : (e > 63 ? 63 : e);
  out[OUT_SEL + b] = (float)e;
  wsi[WS_SEL + b]  = e;
  atomicAdd(&lh[e], 1);
  __syncthreads();
  if (t < NMODELS && lh[t] > 0) atomicAdd(&wsi[WS_HIST + t], lh[t]);
}

__global__ void k_prefix(int* __restrict__ wsi) {  // 1 block, 64 threads (one wave)
  int t = threadIdx.x;      // t = expert id
  int c = wsi[WS_HIST + t];
  int x = c;
  #pragma unroll
  for (int d = 1; d < 64; d <<= 1) {
    int y = __shfl_up(x, d, 64);
    if (t >= d) x += y;
  }
  int off = x - c;                 // exclusive prefix of counts
  wsi[WS_CUR + t] = off;           // scatter cursor starts at segment base
  int ntile_me = (c + 63) >> 6;
  int tx = ntile_me;
  #pragma unroll
  for (int d = 1; d < 64; d <<= 1) {
    int y = __shfl_up(tx, d, 64);
    if (t >= d) tx += y;
  }
  int tbase = tx - ntile_me;
  for (int k = 0; k < ntile_me; ++k) {
    int rem = c - k * 64;
    wsi[WS_TILES + (tbase + k) * 3 + 0] = t;
    wsi[WS_TILES + (tbase + k) * 3 + 1] = off + k * 64;
    wsi[WS_TILES + (tbase + k) * 3 + 2] = rem < 64 ? rem : 64;
  }
  if (t == 63) wsi[WS_NT] = tx;
}

__global__ void k_scatter(int* __restrict__ wsi) {
  __shared__ int lc[NMODELS];
  __shared__ int lbase[NMODELS];
  int t = threadIdx.x;
  if (t < NMODELS) lc[t] = 0;
  __syncthreads();
  int b = blockIdx.x * 256 + t;
  int e = wsi[WS_SEL + b];
  int r = atomicAdd(&lc[e], 1);
  __syncthreads();
  if (t < NMODELS) {
    int c = lc[t];
    lbase[t] = (c > 0) ? atomicAdd(&wsi[WS_CUR + t], c) : 0;
  }
  __syncthreads();
  wsi[WS_PERM + lbase[e] + r] = b;
}

#define LOADB(bias)                                                          \
  { const float4* bp = reinterpret_cast<const float4*>((bias) + j0);         \
    float4 b0v = bp[0], b1v = bp[1], b2v = bp[2], b3v = bp[3];               \
    acc[0]=b0v.x; acc[1]=b0v.y; acc[2]=b0v.z; acc[3]=b0v.w;                  \
    acc[4]=b1v.x; acc[5]=b1v.y; acc[6]=b1v.z; acc[7]=b1v.w;                  \
    acc[8]=b2v.x; acc[9]=b2v.y; acc[10]=b2v.z; acc[11]=b2v.w;                \
    acc[12]=b3v.x; acc[13]=b3v.y; acc[14]=b3v.z; acc[15]=b3v.w; }

#define FMA16(hi)                                                            \
  acc[0]=fmaf(hi,w0.x,acc[0]);  acc[1]=fmaf(hi,w0.y,acc[1]);                 \
  acc[2]=fmaf(hi,w0.z,acc[2]);  acc[3]=fmaf(hi,w0.w,acc[3]);                 \
  acc[4]=fmaf(hi,w1.x,acc[4]);  acc[5]=fmaf(hi,w1.y,acc[5]);                 \
  acc[6]=fmaf(hi,w1.z,acc[6]);  acc[7]=fmaf(hi,w1.w,acc[7]);                 \
  acc[8]=fmaf(hi,w2.x,acc[8]);  acc[9]=fmaf(hi,w2.y,acc[9]);                 \
  acc[10]=fmaf(hi,w2.z,acc[10]); acc[11]=fmaf(hi,w2.w,acc[11]);              \
  acc[12]=fmaf(hi,w3.x,acc[12]); acc[13]=fmaf(hi,w3.y,acc[13]);              \
  acc[14]=fmaf(hi,w3.z,acc[14]); acc[15]=fmaf(hi,w3.w,acc[15]);

// dst[s][j0..j0+15] = relu(src[s][:] @ W + bias)   (W: 64x64 row-major)
__device__ __forceinline__ void mm64(const float* __restrict__ W,
                                     const float* __restrict__ bias,
                                     const float* src, float* dst,
                                     int s, int j0) {
  float acc[16];
  LOADB(bias);
  const float* Wp = W + j0;
  #pragma unroll 8
  for (int i = 0; i < HID; ++i) {
    float hi = src[s * LSTR + i];
    const float4* wr = reinterpret_cast<const float4*>(Wp + i * HID);
    float4 w0 = wr[0], w1 = wr[1], w2 = wr[2], w3 = wr[3];
    FMA16(hi);
  }
  #pragma unroll
  for (int t2 = 0; t2 < 16; ++t2)
    dst[s * LSTR + j0 + t2] = fmaxf(acc[t2], 0.0f);
}

// h3 = relu(src @ W + bias); accumulate 64x3 head partials into pa (and pb)
template <bool DUAL>
__device__ __forceinline__ void l3l4(const float* __restrict__ W,
                                     const float* __restrict__ bias,
                                     const float* src, int s, int j0,
                                     const float* w4a, float* pa,
                                     const float* w4b, float* pb) {
  float acc[16];
  LOADB(bias);
  const float* Wp = W + j0;
  #pragma unroll 8
  for (int i = 0; i < HID; ++i) {
    float hi = src[s * LSTR + i];
    const float4* wr = reinterpret_cast<const float4*>(Wp + i * HID);
    float4 w0 = wr[0], w1 = wr[1], w2 = wr[2], w3 = wr[3];
    FMA16(hi);
  }
  #pragma unroll
  for (int jj = 0; jj < 16; ++jj) {
    float h = fmaxf(acc[jj], 0.0f);
    int j = j0 + jj;
    pa[0] = fmaf(h, w4a[j * 3 + 0], pa[0]);
    pa[1] = fmaf(h, w4a[j * 3 + 1], pa[1]);
    pa[2] = fmaf(h, w4a[j * 3 + 2], pa[2]);
    if (DUAL) {
      pb[0] = fmaf(h, w4b[j * 3 + 0], pb[0]);
      pb[1] = fmaf(h, w4b[j * 3 + 1], pb[1]);
      pb[2] = fmaf(h, w4b[j * 3 + 2], pb[2]);
    }
  }
}

__global__ __launch_bounds__(256) void k_main(
    const float* __restrict__ in,
    const float* __restrict__ W0, const float* __restrict__ b0,
    const float* __restrict__ W1, const float* __restrict__ b1,
    const float* __restrict__ W2, const float* __restrict__ b2,
    const float* __restrict__ W3, const float* __restrict__ b3,
    const float* __restrict__ W4, const float* __restrict__ b4,
    const int* __restrict__ wsi, float* __restrict__ out) {
  __shared__ float Ah[64 * LSTR];
  __shared__ float Bh[64 * LSTR];
  __shared__ float Ch[64 * LSTR];
  __shared__ float w4s[HID * 3], w4e[HID * 3];
  __shared__ int sidx[64];

  int nt = wsi[WS_NT];
  int g = blockIdx.x;
  if (g >= nt) return;
  int e     = __builtin_amdgcn_readfirstlane(wsi[WS_TILES + g * 3 + 0]);
  int start = __builtin_amdgcn_readfirstlane(wsi[WS_TILES + g * 3 + 1]);
  int cnt   = __builtin_amdgcn_readfirstlane(wsi[WS_TILES + g * 3 + 2]);

  int tid = threadIdx.x;
  int s = tid >> 2, q = tid & 3, j0 = q * 16;
  if (tid < 64) sidx[tid] = (tid < cnt) ? wsi[WS_PERM + start + tid] : -1;
  if (tid < HID * 3) {
    w4s[tid] = W4[tid];
    w4e[tid] = W4[(e + 1) * HID * 3 + tid];
  }
  __syncthreads();
  int idx = sidx[s];

  // ---- L0: x(6) -> Ah (relu) ----
  {
    float xv[6];
    if (idx >= 0) {
      #pragma unroll
      for (int i = 0; i < 6; ++i) xv[i] = in[(size_t)idx * 6 + i];
    } else {
      #pragma unroll
      for (int i = 0; i < 6; ++i) xv[i] = 0.0f;
    }
    float acc[16];
    LOADB(b0);
    #pragma unroll
    for (int i = 0; i < 6; ++i) {
      const float4* wr = reinterpret_cast<const float4*>(W0 + i * HID + j0);
      float4 w0 = wr[0], w1 = wr[1], w2 = wr[2], w3 = wr[3];
      float hi = xv[i];
      FMA16(hi);
    }
    #pragma unroll
    for (int t2 = 0; t2 < 16; ++t2)
      Ah[s * LSTR + j0 + t2] = fmaxf(acc[t2], 0.0f);
  }
  __syncthreads();

  // ---- L1: Ah -> Bh (shared W1) ----
  mm64(W1, b1, Ah, Bh, s, j0);
  __syncthreads();

  // ---- L2: Bh -> Ah (shared), Bh -> Ch (expert) ----
  mm64(W2, b2, Bh, Ah, s, j0);
  mm64(W2 + (size_t)(e + 1) * HID * HID, b2 + (e + 1) * HID, Bh, Ch, s, j0);
  __syncthreads();

  // ---- L3 + L4 fused into register partials ----
  const float* W3e = W3 + (size_t)(e + 1) * HID * HID;
  const float* b3e = b3 + (e + 1) * HID;
  float p[12];
  #pragma unroll
  for (int v = 0; v < 12; ++v) p[v] = 0.0f;
  l3l4<true >(W3,  b3,  Ah, s, j0, w4s, p + 0, w4e, p + 3);  // h3ss -> lod0, lod1
  l3l4<false>(W3e, b3e, Ah, s, j0, w4e, p + 6, nullptr, nullptr); // h3se -> lod2
  l3l4<false>(W3e, b3e, Ch, s, j0, w4e, p + 9, nullptr, nullptr); // h3ee -> lod3

  // reduce partials across the 4 threads of each sample
  #pragma unroll
  for (int v = 0; v < 12; ++v) {
    p[v] += __shfl_xor(p[v], 1);
    p[v] += __shfl_xor(p[v], 2);
  }
  if (q == 0 && idx >= 0) {
    const float* b4e = b4 + (e + 1) * 3;
    p[0] += b4[0];  p[1] += b4[1];  p[2] += b4[2];
    p[3] += b4e[0]; p[4] += b4e[1]; p[5] += b4e[2];
    p[6] += b4e[0]; p[7] += b4e[1]; p[8] += b4e[2];
    p[9] += b4e[0]; p[10] += b4e[1]; p[11] += b4e[2];
    float4* op = reinterpret_cast<float4*>(out + (size_t)idx * 12);
    op[0] = make_float4(p[0], p[1], p[2], p[3]);
    op[1] = make_float4(p[4], p[5], p[6], p[7]);
    op[2] = make_float4(p[8], p[9], p[10], p[11]);
  }
}

extern "C" void kernel_launch(void* const* d_in, const int* in_sizes, int n_in,
                              void* d_out, int out_size, void* d_ws, size_t ws_size,
                              hipStream_t stream) {
  const float* in = (const float*)d_in[0];
  const float* W0 = (const float*)d_in[1];
  const float* b0 = (const float*)d_in[2];
  const float* W1 = (const float*)d_in[3];
  const float* b1 = (const float*)d_in[4];
  const float* W2 = (const float*)d_in[5];
  const float* b2 = (const float*)d_in[6];
  const float* W3 = (const float*)d_in[7];
  const float* b3 = (const float*)d_in[8];
  const float* W4 = (const float*)d_in[9];
  const float* b4 = (const float*)d_in[10];
  float* out = (float*)d_out;
  int* wsi = (int*)d_ws;

  hipLaunchKernelGGL(k_init,    dim3(1),    dim3(64),  0, stream, wsi);
  hipLaunchKernelGGL(k_fill,    dim3(2048), dim3(256), 0, stream, out);
  hipLaunchKernelGGL(k_route,   dim3(128),  dim3(256), 0, stream, in, out, wsi);
  hipLaunchKernelGGL(k_prefix,  dim3(1),    dim3(64),  0, stream, wsi);
  hipLaunchKernelGGL(k_scatter, dim3(128),  dim3(256), 0, stream, wsi);
  hipLaunchKernelGGL(k_main,    dim3(MAX_TILES), dim3(256), 0, stream,
                     in, W0, b0, W1, b1, W2, b2, W3, b3, W4, b4, wsi, out);
}

// Round 5
// 210.516 us; speedup vs baseline: 1.7056x; 1.7056x over previous
//
#include <hip/hip_runtime.h>
#include <math.h>

#define NMODELS 64
#define HID     64
#define TS      32          // samples per tile
#define LSTR    65          // LDS row stride (pad) -> conflict-free

// workspace layout (int32 indices)
#define WS_NT    0
#define WS_HIST  16
#define WS_CUR   96
#define WS_TILES 192        // 3 ints per tile
#define MAX_TILES 1088      // 32768/32 + 64
#define WS_SEL   4096
#define WS_PERM  36864

// output layout (float32 indices)
#define OUT_SEL  393216
#define OUT_LOG  425984
#define OUT_PROB 2523136

__global__ void k_fill(float* __restrict__ out, int* __restrict__ wsi) {
  int t = blockIdx.x * 256 + threadIdx.x;   // 524288 threads, 1 float4 each per array
  float4 one = make_float4(1.f, 1.f, 1.f, 1.f);
  float4 pr  = make_float4(0.015625f, 0.015625f, 0.015625f, 0.015625f);
  reinterpret_cast<float4*>(out + OUT_LOG)[t]  = one;
  reinterpret_cast<float4*>(out + OUT_PROB)[t] = pr;
  if (blockIdx.x == 0 && threadIdx.x < NMODELS) wsi[WS_HIST + threadIdx.x] = 0;
}

__global__ void k_route(const float* __restrict__ in, float* __restrict__ out,
                        int* __restrict__ wsi) {
  __shared__ int lh[NMODELS];
  int t = threadIdx.x;
  if (t < NMODELS) lh[t] = 0;
  __syncthreads();
  int b = blockIdx.x * 256 + t;
  float x = in[b * 6 + 0];
  float z = in[b * 6 + 2];
  const float TWO_PI = 6.283185307179586476925286766559f;
  // f64 atan2 rounded to f32 ~= correctly-rounded f32 atan2 (matches numpy);
  // remaining chain is IEEE-exact f32, bit-identical to the reference.
  float ang = (float)atan2((double)z, (double)x);
  float tt  = ang + TWO_PI;
  float m   = fmodf(tt, TWO_PI);
  float a   = m / TWO_PI * 64.0f;
  int e = (int)floorf(a);
  e = e < 0 ? 0 : (e > 63 ? 63 : e);
  out[OUT_SEL + b] = (float)e;
  wsi[WS_SEL + b]  = e;
  atomicAdd(&lh[e], 1);
  __syncthreads();
  if (t < NMODELS && lh[t] > 0) atomicAdd(&wsi[WS_HIST + t], lh[t]);
}

__global__ void k_prefix(int* __restrict__ wsi) {  // 1 block, 64 threads (one wave)
  int t = threadIdx.x;      // t = expert id
  int c = wsi[WS_HIST + t];
  int x = c;
  #pragma unroll
  for (int d = 1; d < 64; d <<= 1) {
    int y = __shfl_up(x, d, 64);
    if (t >= d) x += y;
  }
  int off = x - c;                 // exclusive prefix of counts
  wsi[WS_CUR + t] = off;           // scatter cursor starts at segment base
  int ntile_me = (c + TS - 1) >> 5;
  int tx = ntile_me;
  #pragma unroll
  for (int d = 1; d < 64; d <<= 1) {
    int y = __shfl_up(tx, d, 64);
    if (t >= d) tx += y;
  }
  int tbase = tx - ntile_me;
  for (int k = 0; k < ntile_me; ++k) {
    int rem = c - k * TS;
    wsi[WS_TILES + (tbase + k) * 3 + 0] = t;
    wsi[WS_TILES + (tbase + k) * 3 + 1] = off + k * TS;
    wsi[WS_TILES + (tbase + k) * 3 + 2] = rem < TS ? rem : TS;
  }
  if (t == 63) wsi[WS_NT] = tx;
}

__global__ void k_scatter(int* __restrict__ wsi) {
  __shared__ int lc[NMODELS];
  __shared__ int lbase[NMODELS];
  int t = threadIdx.x;
  if (t < NMODELS) lc[t] = 0;
  __syncthreads();
  int b = blockIdx.x * 256 + t;
  int e = wsi[WS_SEL + b];
  int r = atomicAdd(&lc[e], 1);
  __syncthreads();
  if (t < NMODELS) {
    int c = lc[t];
    lbase[t] = (c > 0) ? atomicAdd(&wsi[WS_CUR + t], c) : 0;
  }
  __syncthreads();
  wsi[WS_PERM + lbase[e] + r] = b;
}

#define FMA8A(hi, wa, wb, a)                                                 \
  a[0]=fmaf(hi,wa.x,a[0]); a[1]=fmaf(hi,wa.y,a[1]);                          \
  a[2]=fmaf(hi,wa.z,a[2]); a[3]=fmaf(hi,wa.w,a[3]);                          \
  a[4]=fmaf(hi,wb.x,a[4]); a[5]=fmaf(hi,wb.y,a[5]);                          \
  a[6]=fmaf(hi,wb.z,a[6]); a[7]=fmaf(hi,wb.w,a[7]);

#define LOADB8(bias, a)                                                      \
  { const float4* bp = reinterpret_cast<const float4*>((bias) + j0);         \
    float4 u = bp[0], v = bp[1];                                             \
    a[0]=u.x; a[1]=u.y; a[2]=u.z; a[3]=u.w;                                  \
    a[4]=v.x; a[5]=v.y; a[6]=v.z; a[7]=v.w; }

// acc[0..7] = bias[j0..j0+7] + src[s][:] @ W[:, j0..j0+7]
__device__ __forceinline__ void mmacc(const float* __restrict__ W,
                                      const float* __restrict__ bias,
                                      const float* src, int s, int j0,
                                      float acc[8]) {
  LOADB8(bias, acc);
  const float* Wp = W + j0;
  const float* hp = src + s * LSTR;
  #pragma unroll 4
  for (int i = 0; i < HID; ++i) {
    float hi = hp[i];
    const float4* wr = reinterpret_cast<const float4*>(Wp + (size_t)i * HID);
    float4 wa = wr[0], wb = wr[1];
    FMA8A(hi, wa, wb, acc);
  }
}

// two matmuls sharing one pass over src (one LDS h-read feeds both)
__device__ __forceinline__ void mmacc2(const float* __restrict__ Wa_,
                                       const float* __restrict__ ba_,
                                       const float* __restrict__ Wb_,
                                       const float* __restrict__ bb_,
                                       const float* src, int s, int j0,
                                       float a1[8], float a2[8]) {
  LOADB8(ba_, a1);
  LOADB8(bb_, a2);
  const float* Wpa = Wa_ + j0;
  const float* Wpb = Wb_ + j0;
  const float* hp = src + s * LSTR;
  #pragma unroll 2
  for (int i = 0; i < HID; ++i) {
    float hi = hp[i];
    const float4* wra = reinterpret_cast<const float4*>(Wpa + (size_t)i * HID);
    const float4* wrb = reinterpret_cast<const float4*>(Wpb + (size_t)i * HID);
    float4 wa = wra[0], wb = wra[1];
    float4 wc = wrb[0], wd = wrb[1];
    FMA8A(hi, wa, wb, a1);
    FMA8A(hi, wc, wd, a2);
  }
}

__global__ __launch_bounds__(256) void k_main(
    const float* __restrict__ in,
    const float* __restrict__ W0, const float* __restrict__ b0,
    const float* __restrict__ W1, const float* __restrict__ b1,
    const float* __restrict__ W2, const float* __restrict__ b2,
    const float* __restrict__ W3, const float* __restrict__ b3,
    const float* __restrict__ W4, const float* __restrict__ b4,
    const int* __restrict__ wsi, float* __restrict__ out) {
  __shared__ float Ah[TS * LSTR];
  __shared__ float Bh[TS * LSTR];
  __shared__ float Ch[TS * LSTR];
  __shared__ float w4s[HID * 3], w4e[HID * 3];
  __shared__ int sidx[TS];

  int g = blockIdx.x;
  if (g >= wsi[WS_NT]) return;
  int e     = __builtin_amdgcn_readfirstlane(wsi[WS_TILES + g * 3 + 0]);
  int start = __builtin_amdgcn_readfirstlane(wsi[WS_TILES + g * 3 + 1]);
  int cnt   = __builtin_amdgcn_readfirstlane(wsi[WS_TILES + g * 3 + 2]);

  int tid = threadIdx.x;
  int s = tid >> 3, q = tid & 7, j0 = q * 8;
  if (tid < TS) sidx[tid] = (tid < cnt) ? wsi[WS_PERM + start + tid] : -1;
  if (tid < HID * 3) {
    w4s[tid] = W4[tid];
    w4e[tid] = W4[(e + 1) * HID * 3 + tid];
  }
  __syncthreads();
  int idx = sidx[s];

  // ---- L0: x(6) -> Ah ----
  {
    float acc[8];
    LOADB8(b0, acc);
    #pragma unroll
    for (int i = 0; i < 6; ++i) {
      float hi = (idx >= 0) ? in[(size_t)idx * 6 + i] : 0.0f;
      const float4* wr = reinterpret_cast<const float4*>(W0 + i * HID + j0);
      float4 wa = wr[0], wb = wr[1];
      FMA8A(hi, wa, wb, acc);
    }
    #pragma unroll
    for (int k = 0; k < 8; ++k) Ah[s * LSTR + j0 + k] = fmaxf(acc[k], 0.0f);
  }
  __syncthreads();

  // ---- L1: Ah -> Bh (shared W1) ----
  {
    float acc[8];
    mmacc(W1, b1, Ah, s, j0, acc);
    #pragma unroll
    for (int k = 0; k < 8; ++k) Bh[s * LSTR + j0 + k] = fmaxf(acc[k], 0.0f);
  }
  __syncthreads();

  // ---- L2 shared + expert fused (one pass over Bh) ----
  {
    float a1[8], a2[8];
    mmacc2(W2, b2, W2 + (size_t)(e + 1) * HID * HID, b2 + (e + 1) * HID,
           Bh, s, j0, a1, a2);
    #pragma unroll
    for (int k = 0; k < 8; ++k) {
      Ch[s * LSTR + j0 + k] = fmaxf(a1[k], 0.0f);   // h3s
      Ah[s * LSTR + j0 + k] = fmaxf(a2[k], 0.0f);   // h3e (h1 dead)
    }
  }
  __syncthreads();

  const float* W3e = W3 + (size_t)(e + 1) * HID * HID;
  const float* b3e = b3 + (e + 1) * HID;
  float pr[12];
  #pragma unroll
  for (int v = 0; v < 12; ++v) pr[v] = 0.0f;

  // ---- L3 shared + expert fused from h3s (Ch); heads from registers ----
  {
    float a1[8], a2[8];
    mmacc2(W3, b3, W3e, b3e, Ch, s, j0, a1, a2);
    #pragma unroll
    for (int jj = 0; jj < 8; ++jj) {
      int j = j0 + jj;
      float h = fmaxf(a1[jj], 0.0f);                // h4ss -> lod0 (w4s), lod1 (w4e)
      pr[0] = fmaf(h, w4s[j * 3 + 0], pr[0]);
      pr[1] = fmaf(h, w4s[j * 3 + 1], pr[1]);
      pr[2] = fmaf(h, w4s[j * 3 + 2], pr[2]);
      pr[3] = fmaf(h, w4e[j * 3 + 0], pr[3]);
      pr[4] = fmaf(h, w4e[j * 3 + 1], pr[4]);
      pr[5] = fmaf(h, w4e[j * 3 + 2], pr[5]);
      float g2 = fmaxf(a2[jj], 0.0f);               // h4se -> lod2 (w4e)
      pr[6] = fmaf(g2, w4e[j * 3 + 0], pr[6]);
      pr[7] = fmaf(g2, w4e[j * 3 + 1], pr[7]);
      pr[8] = fmaf(g2, w4e[j * 3 + 2], pr[8]);
    }
  }

  // ---- expert L3 from h3e (Ah); head lod3 ----
  {
    float acc[8];
    mmacc(W3e, b3e, Ah, s, j0, acc);
    #pragma unroll
    for (int jj = 0; jj < 8; ++jj) {
      int j = j0 + jj;
      float h = fmaxf(acc[jj], 0.0f);               // h4ee -> lod3 (w4e)
      pr[9]  = fmaf(h, w4e[j * 3 + 0], pr[9]);
      pr[10] = fmaf(h, w4e[j * 3 + 1], pr[10]);
      pr[11] = fmaf(h, w4e[j * 3 + 2], pr[11]);
    }
  }

  // reduce partials across the 8 threads of each sample
  #pragma unroll
  for (int v = 0; v < 12; ++v) {
    pr[v] += __shfl_xor(pr[v], 1);
    pr[v] += __shfl_xor(pr[v], 2);
    pr[v] += __shfl_xor(pr[v], 4);
  }
  if (q == 0 && idx >= 0) {
    const float* b4e = b4 + (e + 1) * 3;
    pr[0] += b4[0];  pr[1] += b4[1];  pr[2] += b4[2];
    pr[3] += b4e[0]; pr[4] += b4e[1]; pr[5] += b4e[2];
    pr[6] += b4e[0]; pr[7] += b4e[1]; pr[8] += b4e[2];
    pr[9] += b4e[0]; pr[10] += b4e[1]; pr[11] += b4e[2];
    float4* op = reinterpret_cast<float4*>(out + (size_t)idx * 12);
    op[0] = make_float4(pr[0], pr[1], pr[2], pr[3]);
    op[1] = make_float4(pr[4], pr[5], pr[6], pr[7]);
    op[2] = make_float4(pr[8], pr[9], pr[10], pr[11]);
  }
}

extern "C" void kernel_launch(void* const* d_in, const int* in_sizes, int n_in,
                              void* d_out, int out_size, void* d_ws, size_t ws_size,
                              hipStream_t stream) {
  const float* in = (const float*)d_in[0];
  const float* W0 = (const float*)d_in[1];
  const float* b0 = (const float*)d_in[2];
  const float* W1 = (const float*)d_in[3];
  const float* b1 = (const float*)d_in[4];
  const float* W2 = (const float*)d_in[5];
  const float* b2 = (const float*)d_in[6];
  const float* W3 = (const float*)d_in[7];
  const float* b3 = (const float*)d_in[8];
  const float* W4 = (const float*)d_in[9];
  const float* b4 = (const float*)d_in[10];
  float* out = (float*)d_out;
  int* wsi = (int*)d_ws;

  hipLaunchKernelGGL(k_fill,    dim3(2048), dim3(256), 0, stream, out, wsi);
  hipLaunchKernelGGL(k_route,   dim3(128),  dim3(256), 0, stream, in, out, wsi);
  hipLaunchKernelGGL(k_prefix,  dim3(1),    dim3(64),  0, stream, wsi);
  hipLaunchKernelGGL(k_scatter, dim3(128),  dim3(256), 0, stream, wsi);
  hipLaunchKernelGGL(k_main,    dim3(MAX_TILES), dim3(256), 0, stream,
                     in, W0, b0, W1, b1, W2, b2, W3, b3, W4, b4, wsi, out);
}